// Round 15
// baseline (147.127 us; speedup 1.0000x reference)
//
#include <hip/hip_runtime.h>

typedef unsigned short u16;
typedef unsigned int u32;
typedef __attribute__((ext_vector_type(4))) float f32x4;
typedef __attribute__((ext_vector_type(8))) __bf16 bf16x8;

#define NQ 2048
#define NK 4096
#define SCALE 0.125f
#define LOG2E 1.44269504088896f

__device__ __forceinline__ u16 f2bf(float f) {
  u32 x = __float_as_uint(f);
  return (u16)((x + 0x7fffu + ((x >> 16) & 1u)) >> 16);
}

__device__ __forceinline__ float bf2f(u16 b) {
  return __uint_as_float(((u32)b) << 16);
}

// XOR-swizzled byte offset for 64-col (128B-row) bf16 LDS tiles (G4 fix)
__device__ __forceinline__ int swz(int row, int colbyte) {
  return row * 128 + (colbyte ^ ((row & 7) << 4));
}

__device__ __forceinline__ void async16(u16* lds, const u16* g) {
  __builtin_amdgcn_global_load_lds(
      (const __attribute__((address_space(1))) void*)g,
      (__attribute__((address_space(3))) void*)lds, 16, 0, 0);
}

__device__ __forceinline__ f32x4 mfma16(bf16x8 a, bf16x8 b, f32x4 c) {
  return __builtin_amdgcn_mfma_f32_16x16x32_bf16(a, b, c, 0, 0, 0);
}

// tree max over 16 values (4 serial levels)
__device__ __forceinline__ float max16(const f32x4* s) {
  float a = fmaxf(fmaxf(s[0][0], s[0][1]), fmaxf(s[0][2], s[0][3]));
  float b = fmaxf(fmaxf(s[1][0], s[1][1]), fmaxf(s[1][2], s[1][3]));
  float c = fmaxf(fmaxf(s[2][0], s[2][1]), fmaxf(s[2][2], s[2][3]));
  float d = fmaxf(fmaxf(s[3][0], s[3][1]), fmaxf(s[3][2], s[3][3]));
  return fmaxf(fmaxf(a, b), fmaxf(c, d));
}

// Merged prep: LDS-tiled weight transposes (blocks 0-511), x cvt (512-2559),
// LN1 (2560-3583, 4 rows/block).
__global__ __launch_bounds__(256) void k_prep(
    const float* __restrict__ Wqkv, const float* __restrict__ Wao,
    const float* __restrict__ Wq, const float* __restrict__ Wkv,
    const float* __restrict__ Wo, const float* __restrict__ x,
    const float* __restrict__ qx, const float* __restrict__ ln1g,
    const float* __restrict__ ln1b,
    u16* __restrict__ o_qkv, u16* __restrict__ o_ao, u16* __restrict__ o_q,
    u16* __restrict__ o_kv, u16* __restrict__ o_o, u16* __restrict__ x_bf,
    u16* __restrict__ xn_bf) {
  __shared__ float lds[64][65];
  int bid = blockIdx.x;
  int t = threadIdx.x;
  if (bid < 512) {
    int n_tile = bid >> 3, k_tile = bid & 7;
    int n0 = n_tile * 64, k0 = k_tile * 64;
    const float* in;
    u16* out;
    int N, nbase;
    if (n0 < 1536)      { in = Wqkv; out = o_qkv; N = 1536; nbase = 0; }
    else if (n0 < 2048) { in = Wao;  out = o_ao;  N = 512;  nbase = 1536; }
    else if (n0 < 2560) { in = Wq;   out = o_q;   N = 512;  nbase = 2048; }
    else if (n0 < 3584) { in = Wkv;  out = o_kv;  N = 1024; nbase = 2560; }
    else                { in = Wo;   out = o_o;   N = 512;  nbase = 3584; }
    int nl0 = n0 - nbase;
    int qr = t >> 4, c4 = (t & 15) * 4;
#pragma unroll
    for (int j = 0; j < 4; j++) {
      int kr = qr + j * 16;
      float4 v = *(const float4*)(in + (size_t)(k0 + kr) * N + nl0 + c4);
      lds[kr][c4] = v.x;
      lds[kr][c4 + 1] = v.y;
      lds[kr][c4 + 2] = v.z;
      lds[kr][c4 + 3] = v.w;
    }
    __syncthreads();
#pragma unroll
    for (int j = 0; j < 4; j++) {
      int nr = qr + j * 16;
      u16 o4[4];
#pragma unroll
      for (int i = 0; i < 4; i++) o4[i] = f2bf(lds[c4 + i][nr]);
      *(uint2*)(out + (size_t)(nl0 + nr) * 512 + k0 + c4) = *(uint2*)o4;
    }
  } else if (bid < 2560) {
    size_t i = ((size_t)(bid - 512) * 256 + t) * 8;
    float v[8];
    *(float4*)&v[0] = *(const float4*)(x + i);
    *(float4*)&v[4] = *(const float4*)(x + i + 4);
    u16 o[8];
#pragma unroll
    for (int j = 0; j < 8; j++) o[j] = f2bf(v[j]);
    *(uint4*)(x_bf + i) = *(uint4*)o;
  } else {
    int row = (bid - 2560) * 4 + (t >> 6);
    int lane = t & 63;
    size_t base = (size_t)row * 512 + lane * 8;
    float v[8];
    *(float4*)&v[0] = *(const float4*)(qx + base);
    *(float4*)&v[4] = *(const float4*)(qx + base + 4);
    float s = 0.f, q = 0.f;
#pragma unroll
    for (int j = 0; j < 8; j++) { s += v[j]; q += v[j] * v[j]; }
#pragma unroll
    for (int d = 1; d < 64; d <<= 1) {
      s += __shfl_xor(s, d, 64);
      q += __shfl_xor(q, d, 64);
    }
    float mean = s * (1.f / 512.f);
    float var = q * (1.f / 512.f) - mean * mean;
    float rstd = rsqrtf(var + 1e-5f);
    float gv[8], bv[8];
    *(float4*)&gv[0] = *(const float4*)(ln1g + lane * 8);
    *(float4*)&gv[4] = *(const float4*)(ln1g + lane * 8 + 4);
    *(float4*)&bv[0] = *(const float4*)(ln1b + lane * 8);
    *(float4*)&bv[4] = *(const float4*)(ln1b + lane * 8 + 4);
    u16 ob[8];
#pragma unroll
    for (int j = 0; j < 8; j++)
      ob[j] = f2bf((v[j] - mean) * rstd * gv[j] + bv[j]);
    *(uint4*)(xn_bf + base) = *(uint4*)ob;
  }
}

// LayerNorm over 512 cols (LN2): xin bf16, residual f32; f32 + bf16 outputs.
__global__ __launch_bounds__(64) void k_ln(const u16* __restrict__ xin,
                                           const float* __restrict__ res,
                                           const float* __restrict__ gg,
                                           const float* __restrict__ bb,
                                           float* __restrict__ fout,
                                           u16* __restrict__ bfout) {
  int row = blockIdx.x, t = threadIdx.x;
  size_t base = (size_t)row * 512 + t * 8;
  u16 xv[8];
  *(uint4*)xv = *(const uint4*)(xin + base);
  float v[8];
#pragma unroll
  for (int j = 0; j < 8; j++) v[j] = bf2f(xv[j]);
  {
    float r2[8];
    *(float4*)&r2[0] = *(const float4*)(res + base);
    *(float4*)&r2[4] = *(const float4*)(res + base + 4);
#pragma unroll
    for (int j = 0; j < 8; j++) v[j] += r2[j];
  }
  float s = 0.f, q = 0.f;
#pragma unroll
  for (int j = 0; j < 8; j++) { s += v[j]; q += v[j] * v[j]; }
#pragma unroll
  for (int d = 1; d < 64; d <<= 1) {
    s += __shfl_xor(s, d, 64);
    q += __shfl_xor(q, d, 64);
  }
  float mean = s * (1.f / 512.f);
  float var = q * (1.f / 512.f) - mean * mean;
  float rstd = rsqrtf(var + 1e-5f);
  float gv[8], bv[8];
  *(float4*)&gv[0] = *(const float4*)(gg + t * 8);
  *(float4*)&gv[4] = *(const float4*)(gg + t * 8 + 4);
  *(float4*)&bv[0] = *(const float4*)(bb + t * 8);
  *(float4*)&bv[4] = *(const float4*)(bb + t * 8 + 4);
  float y[8];
  u16 ob[8];
#pragma unroll
  for (int j = 0; j < 8; j++) {
    y[j] = (v[j] - mean) * rstd * gv[j] + bv[j];
    ob[j] = f2bf(y[j]);
  }
  *(float4*)(fout + base) = *(float4*)&y[0];
  *(float4*)(fout + base + 4) = *(float4*)&y[4];
  *(uint4*)(bfout + base) = *(uint4*)ob;
}

// Merged front GEMMs, one launch:
//   blocks 0-511:   kv = x @ Wkv (128x128 tile, KVPACK epilogue -> kpk/vtp)
//   blocks 512-1279: qkv = xn @ Wqkv (64x128 tile)
__global__ __launch_bounds__(256) void k_mm0(
    const u16* __restrict__ xb, const u16* __restrict__ wkv,
    const u16* __restrict__ xn, const u16* __restrict__ wqkv,
    u16* __restrict__ kpk, u16* __restrict__ vtp, u16* __restrict__ qkv) {
  __shared__ u16 As[8192];
  __shared__ u16 Bs[8192];
  const int tid = threadIdx.x;
  const int lane = tid & 63, wid = tid >> 6;
  const int lr = lane & 15, g = lane >> 4;
  const int wr = wid >> 1, wc = wid & 1;
  const int srow = wid * 8 + (lane >> 3);
  const int scol = ((lane & 7) ^ (lane >> 3)) << 3;
  u16* lA = As + wid * 512;
  u16* lB = Bs + wid * 512;
  const size_t rK = (size_t)32 * 512;
  int bid = blockIdx.x;
  if (bid < 512) {
    int bx = bid & 7, by = bid >> 3;
    const int rowBase = by * 128, colBase = bx * 128;
    f32x4 acc[4][4] = {};
    const u16* gA = xb + (size_t)(rowBase + srow) * 512 + scol;
    const u16* gB = wkv + (size_t)(colBase + srow) * 512 + scol;
    for (int k0 = 0; k0 < 512; k0 += 64) {
#pragma unroll
      for (int r = 0; r < 4; r++) async16(lA + r * 2048, gA + r * rK + k0);
#pragma unroll
      for (int r = 0; r < 4; r++) async16(lB + r * 2048, gB + r * rK + k0);
      __syncthreads();
#pragma unroll
      for (int kk = 0; kk < 2; kk++) {
        bf16x8 af[4], bw[4];
#pragma unroll
        for (int fm = 0; fm < 4; fm++) {
          int row = wr * 64 + fm * 16 + lr;
          af[fm] = *(const bf16x8*)((const char*)As + row * 128 +
                                    (((kk * 4 + g) ^ (row & 7)) << 4));
        }
#pragma unroll
        for (int fn = 0; fn < 4; fn++) {
          int row = wc * 64 + fn * 16 + lr;
          bw[fn] = *(const bf16x8*)((const char*)Bs + row * 128 +
                                    (((kk * 4 + g) ^ (row & 7)) << 4));
        }
#pragma unroll
        for (int fm = 0; fm < 4; fm++)
#pragma unroll
          for (int fn = 0; fn < 4; fn++)
            acc[fm][fn] = mfma16(af[fm], bw[fn], acc[fm][fn]);
      }
      __syncthreads();
    }
#pragma unroll
    for (int fm = 0; fm < 4; fm++) {
#pragma unroll
      for (int fn = 0; fn < 4; fn++) {
        int row = rowBase + wr * 64 + fm * 16 + g * 4;
        int col = colBase + wc * 64 + fn * 16 + lr;
        int b = row >> 12, n = row & 4095, kt = n >> 6, key0 = n & 63;
        int h = (col >> 6) & 7, d = col & 63;
        size_t tbase = ((size_t)(((b << 3) + h) << 6) + kt) * 4096;
        if (col < 512) {
          u16* kd = kpk + tbase + (size_t)key0 * 64 + d;
          kd[0] = f2bf(acc[fm][fn][0]);
          kd[64] = f2bf(acc[fm][fn][1]);
          kd[128] = f2bf(acc[fm][fn][2]);
          kd[192] = f2bf(acc[fm][fn][3]);
        } else {
          u16 p4[4] = {f2bf(acc[fm][fn][0]), f2bf(acc[fm][fn][1]),
                       f2bf(acc[fm][fn][2]), f2bf(acc[fm][fn][3])};
          *(uint2*)(vtp + tbase + (size_t)d * 64 + key0) = *(uint2*)p4;
        }
      }
    }
  } else {
    int j = bid - 512;
    int bx = j % 12, by = j / 12;
    const int rowBase = by * 64, colBase = bx * 128;
    f32x4 acc[2][4] = {};
    const u16* gA = xn + (size_t)(rowBase + srow) * 512 + scol;
    const u16* gB = wqkv + (size_t)(colBase + srow) * 512 + scol;
    for (int k0 = 0; k0 < 512; k0 += 64) {
#pragma unroll
      for (int r = 0; r < 2; r++) async16(lA + r * 2048, gA + r * rK + k0);
#pragma unroll
      for (int r = 0; r < 4; r++) async16(lB + r * 2048, gB + r * rK + k0);
      __syncthreads();
#pragma unroll
      for (int kk = 0; kk < 2; kk++) {
        bf16x8 af[2], bw[4];
#pragma unroll
        for (int fm = 0; fm < 2; fm++) {
          int row = wr * 32 + fm * 16 + lr;
          af[fm] = *(const bf16x8*)((const char*)As + row * 128 +
                                    (((kk * 4 + g) ^ (row & 7)) << 4));
        }
#pragma unroll
        for (int fn = 0; fn < 4; fn++) {
          int row = wc * 64 + fn * 16 + lr;
          bw[fn] = *(const bf16x8*)((const char*)Bs + row * 128 +
                                    (((kk * 4 + g) ^ (row & 7)) << 4));
        }
#pragma unroll
        for (int fm = 0; fm < 2; fm++)
#pragma unroll
          for (int fn = 0; fn < 4; fn++)
            acc[fm][fn] = mfma16(af[fm], bw[fn], acc[fm][fn]);
      }
      __syncthreads();
    }
#pragma unroll
    for (int fm = 0; fm < 2; fm++) {
#pragma unroll
      for (int fn = 0; fn < 4; fn++) {
        int row = rowBase + wr * 32 + fm * 16 + g * 4;
        int col = colBase + wc * 64 + fn * 16 + lr;
#pragma unroll
        for (int r = 0; r < 4; r++)
          qkv[(size_t)(row + r) * 1536 + col] = f2bf(acc[fm][fn][r]);
      }
    }
  }
}

// Small GEMM: 64x64 tile, BK=64, 4 waves (2x2, each 32x32).
template <bool BIAS, bool OBF16>
__global__ __launch_bounds__(256) void k_gemm3(const u16* __restrict__ A,
                                               const u16* __restrict__ Bt,
                                               const float* __restrict__ bias,
                                               void* __restrict__ C, int M, int N, int K) {
  __shared__ u16 As[4096];
  __shared__ u16 Bs[4096];
  const int tid = threadIdx.x;
  const int lane = tid & 63, wid = tid >> 6;
  const int lr = lane & 15, g = lane >> 4;
  const int wr = wid >> 1, wc = wid & 1;
  const int rowBase = blockIdx.y * 64, colBase = blockIdx.x * 64;
  f32x4 acc[2][2] = {};
  const int srow = wid * 8 + (lane >> 3);
  const int scol = ((lane & 7) ^ (lane >> 3)) << 3;
  const u16* gA = A + (size_t)(rowBase + srow) * K + scol;
  const u16* gB = Bt + (size_t)(colBase + srow) * K + scol;
  u16* lA = As + wid * 512;
  u16* lB = Bs + wid * 512;
  const size_t rK = (size_t)32 * K;
  for (int k0 = 0; k0 < K; k0 += 64) {
#pragma unroll
    for (int r = 0; r < 2; r++) async16(lA + r * 2048, gA + r * rK + k0);
#pragma unroll
    for (int r = 0; r < 2; r++) async16(lB + r * 2048, gB + r * rK + k0);
    __syncthreads();
#pragma unroll
    for (int kk = 0; kk < 2; kk++) {
      bf16x8 af[2], bw[2];
#pragma unroll
      for (int fm = 0; fm < 2; fm++) {
        int row = wr * 32 + fm * 16 + lr;
        af[fm] = *(const bf16x8*)((const char*)As + row * 128 +
                                  (((kk * 4 + g) ^ (row & 7)) << 4));
      }
#pragma unroll
      for (int fn = 0; fn < 2; fn++) {
        int row = wc * 32 + fn * 16 + lr;
        bw[fn] = *(const bf16x8*)((const char*)Bs + row * 128 +
                                  (((kk * 4 + g) ^ (row & 7)) << 4));
      }
#pragma unroll
      for (int fm = 0; fm < 2; fm++)
#pragma unroll
        for (int fn = 0; fn < 2; fn++)
          acc[fm][fn] = mfma16(af[fm], bw[fn], acc[fm][fn]);
    }
    __syncthreads();
  }
#pragma unroll
  for (int fm = 0; fm < 2; fm++) {
#pragma unroll
    for (int fn = 0; fn < 2; fn++) {
      int row = rowBase + wr * 32 + fm * 16 + g * 4;
      int col = colBase + wc * 32 + fn * 16 + lr;
      float bvv = BIAS ? bias[col] : 0.f;
#pragma unroll
      for (int r = 0; r < 4; r++) {
        float v = acc[fm][fn][r] + bvv;
        if (OBF16)
          ((u16*)C)[(size_t)(row + r) * N + col] = f2bf(v);
        else
          ((float*)C)[(size_t)(row + r) * N + col] = v;
      }
    }
  }
}

// Chunked local attention: one block per (b, h, chunk of 64).
__global__ __launch_bounds__(256) void k_local(const u16* __restrict__ qkv,
                                               u16* __restrict__ oattn) {
  int bid = blockIdx.x;
  int m = bid & 31, h = (bid >> 5) & 7, b = bid >> 8;
  __shared__ u16 Qs[4096], Ks[4096], Vt[4096], Ps[4096];
  int t = threadIdx.x;
  {
    int i = t >> 2, c0 = (t & 3) * 16;
    const u16* base = qkv + (size_t)(b * NQ + m * 64 + i) * 1536 + c0;
    uint4 q0 = *(const uint4*)(base + h * 64);
    uint4 q1 = *(const uint4*)(base + h * 64 + 8);
    uint4 k0 = *(const uint4*)(base + 512 + h * 64);
    uint4 k1 = *(const uint4*)(base + 512 + h * 64 + 8);
    uint4 v0 = *(const uint4*)(base + 1024 + h * 64);
    uint4 v1 = *(const uint4*)(base + 1024 + h * 64 + 8);
    *(uint4*)((char*)Qs + swz(i, c0 * 2)) = q0;
    *(uint4*)((char*)Qs + swz(i, c0 * 2 + 16)) = q1;
    *(uint4*)((char*)Ks + swz(i, c0 * 2)) = k0;
    *(uint4*)((char*)Ks + swz(i, c0 * 2 + 16)) = k1;
    u16 vv[16];
    *(uint4*)&vv[0] = v0;
    *(uint4*)&vv[8] = v1;
#pragma unroll
    for (int j = 0; j < 16; j++) {
      int d = c0 + j;
      *(u16*)((char*)Vt + swz(d, i * 2)) = vv[j];  // Vt[d][key]
    }
  }
  __syncthreads();
  int lane = t & 63, w = t >> 6, lr = lane & 15, g = lane >> 4;
  bf16x8 aq[2];
#pragma unroll
  for (int kk = 0; kk < 2; kk++)
    aq[kk] = *(const bf16x8*)((const char*)Qs + swz(w * 16 + lr, kk * 64 + g * 16));
  f32x4 s[4] = {};
#pragma unroll
  for (int fn = 0; fn < 4; fn++)
#pragma unroll
    for (int kk = 0; kk < 2; kk++) {
      bf16x8 bk = *(const bf16x8*)((const char*)Ks + swz(fn * 16 + lr, kk * 64 + g * 16));
      s[fn] = mfma16(aq[kk], bk, s[fn]);
    }
  float mx[4], sm[4], p[4][4];
#pragma unroll
  for (int r = 0; r < 4; r++)
    mx[r] = fmaxf(fmaxf(s[0][r], s[1][r]), fmaxf(s[2][r], s[3][r]));
#pragma unroll
  for (int d = 1; d < 16; d <<= 1)
#pragma unroll
    for (int r = 0; r < 4; r++) mx[r] = fmaxf(mx[r], __shfl_xor(mx[r], d, 64));
#pragma unroll
  for (int r = 0; r < 4; r++) {
    float a = 0.f;
#pragma unroll
    for (int fn = 0; fn < 4; fn++) {
      p[fn][r] = exp2f((s[fn][r] - mx[r]) * (SCALE * LOG2E));
      a += p[fn][r];
    }
    sm[r] = a;
  }
#pragma unroll
  for (int d = 1; d < 16; d <<= 1)
#pragma unroll
    for (int r = 0; r < 4; r++) sm[r] += __shfl_xor(sm[r], d, 64);
  float rinv[4];
#pragma unroll
  for (int r = 0; r < 4; r++) rinv[r] = 1.f / sm[r];
#pragma unroll
  for (int fn = 0; fn < 4; fn++)
#pragma unroll
    for (int r = 0; r < 4; r++)
      *(u16*)((char*)Ps + swz(w * 16 + g * 4 + r, (fn * 16 + lr) * 2)) =
          f2bf(p[fn][r] * rinv[r]);
  bf16x8 ap[2];
#pragma unroll
  for (int kk = 0; kk < 2; kk++)
    ap[kk] = *(const bf16x8*)((const char*)Ps + swz(w * 16 + lr, kk * 64 + g * 16));
  f32x4 o[4] = {};
#pragma unroll
  for (int fn = 0; fn < 4; fn++)
#pragma unroll
    for (int kk = 0; kk < 2; kk++) {
      bf16x8 bv = *(const bf16x8*)((const char*)Vt + swz(fn * 16 + lr, kk * 64 + g * 16));
      o[fn] = mfma16(ap[kk], bv, o[fn]);
    }
#pragma unroll
  for (int fn = 0; fn < 4; fn++)
#pragma unroll
    for (int r = 0; r < 4; r++)
      oattn[(size_t)(b * NQ + m * 64 + w * 16 + g * 4 + r) * 512 + h * 64 + fn * 16 + lr] =
          f2bf(o[fn][r]);
}

// Flash cross-attention, split-K=8, swapped QK^T, 32 q-rows/wave, MFMA l-sum,
// LDS-staged K/V dbuf, KEY-PERMUTED K staging -> P stays in registers,
// defer-max, setprio, XCD remap. 32KB LDS.
__global__ __launch_bounds__(256, 4) void k_cross(const u16* __restrict__ q,
                                                  const u16* __restrict__ kpk,
                                                  const u16* __restrict__ vtp,
                                                  u16* __restrict__ opart,
                                                  float* __restrict__ ml) {
  int f = blockIdx.x + 16 * blockIdx.y + 256 * blockIdx.z;
  int xcd = f & 7, j = f >> 3;
  int c = xcd + 8 * (j >> 4);    // c in [0,128): bh x split
  int qt = j & 15, bh = c & 15, split = c >> 4;  // split in [0,8)
  int b = bh >> 3, h = bh & 7;
  int t = threadIdx.x, lane = t & 63, w = t >> 6, lr = lane & 15, g = lane >> 4;
  __shared__ u16 Ks[2][4096], Vs[2][4096];
  const float cs = SCALE * LOG2E;

  bf16x8 ones;
#pragma unroll
  for (int i = 0; i < 8; i++) ones[i] = (__bf16)1.0f;

  int srow = w * 16 + (lane >> 3);
  int scolb = ((lane & 7) ^ (srow & 7)) << 3;  // u16 units
  int kperm = ((srow >> 5) << 5) + (((srow >> 2) & 3) << 3) +
              (((srow >> 4) & 1) << 2) + (srow & 3);
  int ksoff0 = kperm * 64 + scolb;
  int ksoff1 = ksoff0 + 1024;
  int soff0 = srow * 64 + scolb;
  int soff1 = soff0 + 512;
  const u16* ktiles = kpk + ((size_t)(bh * 64 + split * 8) * 4096);
  const u16* vtiles = vtp + ((size_t)(bh * 64 + split * 8) * 4096);

  const u16* qrowL = q + (size_t)(b * NQ + qt * 128 + w * 32 + lr) * 512 + h * 64;
  const u16* qrowH = qrowL + 16 * 512;
  bf16x8 aqL0 = *(const bf16x8*)(qrowL + g * 8);
  bf16x8 aqL1 = *(const bf16x8*)(qrowL + 32 + g * 8);
  bf16x8 aqH0 = *(const bf16x8*)(qrowH + g * 8);
  bf16x8 aqH1 = *(const bf16x8*)(qrowH + 32 + g * 8);

  f32x4 oL[4] = {}, oH[4] = {};
  f32x4 lsumL = {}, lsumH = {};
  float mL = -1e30f, mH = -1e30f;

  async16(&Ks[0][w * 1024], ktiles + ksoff0);
  async16(&Ks[0][w * 1024 + 512], ktiles + ksoff1);
  async16(&Vs[0][w * 1024], vtiles + soff0);
  async16(&Vs[0][w * 1024 + 512], vtiles + soff1);
  __syncthreads();

  int buf = 0;
  for (int kt = 0; kt < 8; kt++) {
    if (kt < 7) {
      const u16* kn = ktiles + (size_t)(kt + 1) * 4096;
      const u16* vn = vtiles + (size_t)(kt + 1) * 4096;
      async16(&Ks[buf ^ 1][w * 1024], kn + ksoff0);
      async16(&Ks[buf ^ 1][w * 1024 + 512], kn + ksoff1);
      async16(&Vs[buf ^ 1][w * 1024], vn + soff0);
      async16(&Vs[buf ^ 1][w * 1024 + 512], vn + soff1);
    }
    f32x4 stL[4], stH[4];
    __builtin_amdgcn_s_setprio(1);
#pragma unroll
    for (int fm = 0; fm < 4; fm++) {
      bf16x8 bk0 = *(const bf16x8*)((const char*)Ks[buf] + swz(fm * 16 + lr, g * 16));
      bf16x8 bk1 = *(const bf16x8*)((const char*)Ks[buf] + swz(fm * 16 + lr, 64 + g * 16));
      stL[fm] = mfma16(bk0, aqL0, (f32x4){0.f, 0.f, 0.f, 0.f});
      stL[fm] = mfma16(bk1, aqL1, stL[fm]);
      stH[fm] = mfma16(bk0, aqH0, (f32x4){0.f, 0.f, 0.f, 0.f});
      stH[fm] = mfma16(bk1, aqH1, stH[fm]);
    }
    __builtin_amdgcn_s_setprio(0);
    // ---- softmax L (in registers) ----
    float tmL = max16(stL);
    tmL = fmaxf(tmL, __shfl_xor(tmL, 16, 64));
    tmL = fmaxf(tmL, __shfl_xor(tmL, 32, 64));
    if (!__all(tmL <= mL + 22.2f)) {
      float mnew = fmaxf(mL, tmL);
      float corr = exp2f((mL - mnew) * cs);
      mL = mnew;
      float c0 = __shfl(corr, g * 4 + 0, 64);
      float c1 = __shfl(corr, g * 4 + 1, 64);
      float c2 = __shfl(corr, g * 4 + 2, 64);
      float c3 = __shfl(corr, g * 4 + 3, 64);
      lsumL[0] *= c0; lsumL[1] *= c1; lsumL[2] *= c2; lsumL[3] *= c3;
#pragma unroll
      for (int fn = 0; fn < 4; fn++) {
        oL[fn][0] *= c0; oL[fn][1] *= c1; oL[fn][2] *= c2; oL[fn][3] *= c3;
      }
    }
    bf16x8 apL0, apL1;
    {
      float mc = mL * cs;
      union { __bf16 hh[8]; bf16x8 v; } u0, u1;
#pragma unroll
      for (int r = 0; r < 4; r++) {
        u0.hh[r]     = (__bf16)exp2f(stL[0][r] * cs - mc);
        u0.hh[4 + r] = (__bf16)exp2f(stL[1][r] * cs - mc);
        u1.hh[r]     = (__bf16)exp2f(stL[2][r] * cs - mc);
        u1.hh[4 + r] = (__bf16)exp2f(stL[3][r] * cs - mc);
      }
      apL0 = u0.v;
      apL1 = u1.v;
    }
    // ---- softmax H ----
    float tmH = max16(stH);
    tmH = fmaxf(tmH, __shfl_xor(tmH, 16, 64));
    tmH = fmaxf(tmH, __shfl_xor(tmH, 32, 64));
    if (!__all(tmH <= mH + 22.2f)) {
      float mnew = fmaxf(mH, tmH);
      float corr = exp2f((mH - mnew) * cs);
      mH = mnew;
      float c0 = __shfl(corr, g * 4 + 0, 64);
      float c1 = __shfl(corr, g * 4 + 1, 64);
      float c2 = __shfl(corr, g * 4 + 2, 64);
      float c3 = __shfl(corr, g * 4 + 3, 64);
      lsumH[0] *= c0; lsumH[1] *= c1; lsumH[2] *= c2; lsumH[3] *= c3;
#pragma unroll
      for (int fn = 0; fn < 4; fn++) {
        oH[fn][0] *= c0; oH[fn][1] *= c1; oH[fn][2] *= c2; oH[fn][3] *= c3;
      }
    }
    bf16x8 apH0, apH1;
    {
      float mc = mH * cs;
      union { __bf16 hh[8]; bf16x8 v; } u0, u1;
#pragma unroll
      for (int r = 0; r < 4; r++) {
        u0.hh[r]     = (__bf16)exp2f(stH[0][r] * cs - mc);
        u0.hh[4 + r] = (__bf16)exp2f(stH[1][r] * cs - mc);
        u1.hh[r]     = (__bf16)exp2f(stH[2][r] * cs - mc);
        u1.hh[4 + r] = (__bf16)exp2f(stH[3][r] * cs - mc);
      }
      apH0 = u0.v;
      apH1 = u1.v;
    }
    // ---- PV + l-sum via ones-MFMA ----
    __builtin_amdgcn_s_setprio(1);
    lsumL = mfma16(apL0, ones, lsumL);
    lsumL = mfma16(apL1, ones, lsumL);
    lsumH = mfma16(apH0, ones, lsumH);
    lsumH = mfma16(apH1, ones, lsumH);
#pragma unroll
    for (int fn = 0; fn < 4; fn++) {
      bf16x8 bv0 = *(const bf16x8*)((const char*)Vs[buf] + swz(fn * 16 + lr, g * 16));
      bf16x8 bv1 = *(const bf16x8*)((const char*)Vs[buf] + swz(fn * 16 + lr, 64 + g * 16));
      oL[fn] = mfma16(apL0, bv0, oL[fn]);
      oL[fn] = mfma16(apL1, bv1, oL[fn]);
      oH[fn] = mfma16(apH0, bv0, oH[fn]);
      oH[fn] = mfma16(apH1, bv1, oH[fn]);
    }
    __builtin_amdgcn_s_setprio(0);
    __syncthreads();
    buf ^= 1;
  }
  size_t sb = ((size_t)(split * 16 + bh) * NQ) + qt * 128 + w * 32;
  {
    float r0 = 1.f / lsumL[0], r1 = 1.f / lsumL[1];
    float r2 = 1.f / lsumL[2], r3 = 1.f / lsumL[3];
#pragma unroll
    for (int fn = 0; fn < 4; fn++) {
      opart[(sb + g * 4 + 0) * 64 + fn * 16 + lr] = f2bf(oL[fn][0] * r0);
      opart[(sb + g * 4 + 1) * 64 + fn * 16 + lr] = f2bf(oL[fn][1] * r1);
      opart[(sb + g * 4 + 2) * 64 + fn * 16 + lr] = f2bf(oL[fn][2] * r2);
      opart[(sb + g * 4 + 3) * 64 + fn * 16 + lr] = f2bf(oL[fn][3] * r3);
    }
  }
  {
    float r0 = 1.f / lsumH[0], r1 = 1.f / lsumH[1];
    float r2 = 1.f / lsumH[2], r3 = 1.f / lsumH[3];
#pragma unroll
    for (int fn = 0; fn < 4; fn++) {
      opart[(sb + 16 + g * 4 + 0) * 64 + fn * 16 + lr] = f2bf(oH[fn][0] * r0);
      opart[(sb + 16 + g * 4 + 1) * 64 + fn * 16 + lr] = f2bf(oH[fn][1] * r1);
      opart[(sb + 16 + g * 4 + 2) * 64 + fn * 16 + lr] = f2bf(oH[fn][2] * r2);
      opart[(sb + 16 + g * 4 + 3) * 64 + fn * 16 + lr] = f2bf(oH[fn][3] * r3);
    }
  }
  if (g == 0) {
    ml[(sb + lr) * 2] = mL;
    ml[(sb + 16 + lr) * 2] = mH;
  }
  if (lr == 0) {
#pragma unroll
    for (int r = 0; r < 4; r++) {
      ml[(sb + g * 4 + r) * 2 + 1] = lsumL[r];
      ml[(sb + 16 + g * 4 + r) * 2 + 1] = lsumH[r];
    }
  }
}

// Combine 8 split-K partials -> co (bf16, merged-head layout).
__global__ __launch_bounds__(256) void k_comb(const u16* __restrict__ opart,
                                              const float* __restrict__ ml,
                                              u16* __restrict__ co) {
  int idx = blockIdx.x * 256 + threadIdx.x;  // 16*2048*8 = 262144
  int c8 = idx & 7;
  int row = (idx >> 3) & 2047;
  int bh = idx >> 14;
  int b = bh >> 3, h = bh & 7;
  const float cs = SCALE * LOG2E;
  float m[8], l[8];
#pragma unroll
  for (int s = 0; s < 8; s++) {
    size_t rb = ((size_t)(s * 16 + bh) * NQ + row);
    m[s] = ml[rb * 2];
    l[s] = ml[rb * 2 + 1];
  }
  float M = m[0];
#pragma unroll
  for (int s = 1; s < 8; s++) M = fmaxf(M, m[s]);
  float wsum = 0.f, wgt[8];
#pragma unroll
  for (int s = 0; s < 8; s++) {
    wgt[s] = l[s] * exp2f((m[s] - M) * cs);
    wsum += wgt[s];
  }
  float rw = 1.f / wsum;
  float acc[8] = {};
#pragma unroll
  for (int s = 0; s < 8; s++) {
    size_t rb = ((size_t)(s * 16 + bh) * NQ + row);
    uint4 pk = *(const uint4*)(opart + rb * 64 + c8 * 8);
    u16 pe[8];
    *(uint4*)pe = pk;
    float wn = wgt[s] * rw;
#pragma unroll
    for (int jj = 0; jj < 8; jj++) acc[jj] += wn * bf2f(pe[jj]);
  }
  u16 ob[8];
#pragma unroll
  for (int jj = 0; jj < 8; jj++) ob[jj] = f2bf(acc[jj]);
  *(uint4*)(co + ((size_t)(b * NQ + row) * 512) + h * 64 + c8 * 8) = *(uint4*)ob;
}

extern "C" void kernel_launch(void* const* d_in, const int* in_sizes, int n_in,
                              void* d_out, int out_size, void* d_ws, size_t ws_size,
                              hipStream_t stream) {
  const float* x    = (const float*)d_in[0];
  const float* qx   = (const float*)d_in[1];
  const float* ln1g = (const float*)d_in[2];
  const float* ln1b = (const float*)d_in[3];
  const float* Wqkv = (const float*)d_in[4];
  const float* Wao  = (const float*)d_in[5];
  const float* bao  = (const float*)d_in[6];
  const float* ln2g = (const float*)d_in[7];
  const float* ln2b = (const float*)d_in[8];
  const float* Wq   = (const float*)d_in[9];
  const float* Wkv  = (const float*)d_in[10];
  const float* Wo   = (const float*)d_in[11];
  const float* bo   = (const float*)d_in[12];
  float* out_p = (float*)d_out;
  float* qin_p = out_p + (size_t)2 * 2048 * 512;

  const size_t MiB = 1048576;
  char* ws = (char*)d_ws;
  u16* w_qkv_t = (u16*)(ws);              // dead after k_mm0
  u16* w_ao_t  = (u16*)(ws + 1572864);    // dead after gemm3-ao
  u16* w_q_t   = (u16*)(ws + 2097152);    // dead after gemm3-q
  u16* w_kv_t  = (u16*)(ws + 2621440);    // dead after k_mm0
  u16* w_o_t   = (u16*)(ws + 3670016);    // alive to end
  u16* kpk     = (u16*)(ws + 4 * MiB);    // 8 MiB, k_mm0 -> k_cross
  u16* vtp     = (u16*)(ws + 12 * MiB);   // 8 MiB, k_mm0 -> k_cross
  u16* x_bf    = (u16*)(ws + 20 * MiB);   // 8 MiB, k_prep -> k_mm0
  u16* oattn_bf = (u16*)(ws + 20 * MiB);  // 4 MiB, k_local -> gemm-ao (x dead)
  u16* ao_bf   = (u16*)(ws + 24 * MiB);   // 4 MiB, gemm-ao -> ln2
  u16* xn_bf   = (u16*)(ws + 28 * MiB);   // 4 MiB, k_prep -> k_mm0
  u16* qin_bf  = (u16*)(ws + 32 * MiB);   // 4 MiB, ln2 -> gemm-q
  u16* opart   = (u16*)(ws + 20 * MiB);   // 32 MiB, k_cross -> k_comb
                                          // (everything 20-52 dead by then)
  u16* qkv_bf  = (u16*)(ws + 36 * MiB);   // 12 MiB, k_mm0 -> k_local
  u16* co_bf   = (u16*)(ws + 4 * MiB);    // 4 MiB, k_comb -> gemm-out
                                          // (kpk dead after k_cross)
  // q and ml live in the `out` half of d_out (overwritten by final gemm)
  u16* q_bf    = (u16*)out_p;             // 4 MiB, gemm-q -> k_cross
  float* ml    = out_p + 1048576;         // 2 MiB, k_cross -> k_comb

  // weights transpose (LDS-tiled) + x cvt + LN1, one launch
  k_prep<<<dim3(512 + 2048 + 1024), 256, 0, stream>>>(
      Wqkv, Wao, Wq, Wkv, Wo, x, qx, ln1g, ln1b,
      w_qkv_t, w_ao_t, w_q_t, w_kv_t, w_o_t, x_bf, xn_bf);
  // kv-GEMM (KVPACK) + qkv-GEMM, one launch
  k_mm0<<<dim3(512 + 768), 256, 0, stream>>>(
      x_bf, w_kv_t, xn_bf, w_qkv_t, kpk, vtp, qkv_bf);
  // local chunked attention (x dead -> oattn)
  k_local<<<dim3(512), 256, 0, stream>>>(qkv_bf, oattn_bf);
  // ao = local_out @ Wao + bao (bf16 out)
  k_gemm3<true, true><<<dim3(512 / 64, 4096 / 64), 256, 0, stream>>>(
      oattn_bf, w_ao_t, bao, ao_bf, 4096, 512, 512);
  // q_in = LN2(ao + qx)  (bf16 ao input)
  k_ln<<<dim3(4096), 64, 0, stream>>>(ao_bf, qx, ln2g, ln2b, qin_p, qin_bf);
  // q = q_in @ Wq (q -> out region scratch)
  k_gemm3<false, true><<<dim3(512 / 64, 4096 / 64), 256, 0, stream>>>(
      qin_bf, w_q_t, nullptr, q_bf, 4096, 512, 512);
  // flash cross attention, split-K=8 (register-P)
  k_cross<<<dim3(16, 16, 8), 256, 0, stream>>>(q_bf, kpk, vtp, opart, ml);
  // combine 8 partials (single pass over opart)
  k_comb<<<dim3(262144 / 256), 256, 0, stream>>>(opart, ml, co_bf);
  // out = cross_out @ Wo + bo (overwrites q/ml scratch)
  k_gemm3<true, false><<<dim3(512 / 64, 4096 / 64), 256, 0, stream>>>(
      co_bf, w_o_t, bo, out_p, 4096, 512, 512);
}

// Round 16
// 144.551 us; speedup vs baseline: 1.0178x; 1.0178x over previous
//
#include <hip/hip_runtime.h>

typedef unsigned short u16;
typedef unsigned int u32;
typedef __attribute__((ext_vector_type(4))) float f32x4;
typedef __attribute__((ext_vector_type(8))) __bf16 bf16x8;

#define NQ 2048
#define NK 4096
#define SCALE 0.125f
#define LOG2E 1.44269504088896f

__device__ __forceinline__ u16 f2bf(float f) {
  u32 x = __float_as_uint(f);
  return (u16)((x + 0x7fffu + ((x >> 16) & 1u)) >> 16);
}

__device__ __forceinline__ float bf2f(u16 b) {
  return __uint_as_float(((u32)b) << 16);
}

// XOR-swizzled byte offset for 64-col (128B-row) bf16 LDS tiles (G4 fix)
__device__ __forceinline__ int swz(int row, int colbyte) {
  return row * 128 + (colbyte ^ ((row & 7) << 4));
}

__device__ __forceinline__ void async16(u16* lds, const u16* g) {
  __builtin_amdgcn_global_load_lds(
      (const __attribute__((address_space(1))) void*)g,
      (__attribute__((address_space(3))) void*)lds, 16, 0, 0);
}

__device__ __forceinline__ f32x4 mfma16(bf16x8 a, bf16x8 b, f32x4 c) {
  return __builtin_amdgcn_mfma_f32_16x16x32_bf16(a, b, c, 0, 0, 0);
}

// tree max over 16 values (4 serial levels)
__device__ __forceinline__ float max16(const f32x4* s) {
  float a = fmaxf(fmaxf(s[0][0], s[0][1]), fmaxf(s[0][2], s[0][3]));
  float b = fmaxf(fmaxf(s[1][0], s[1][1]), fmaxf(s[1][2], s[1][3]));
  float c = fmaxf(fmaxf(s[2][0], s[2][1]), fmaxf(s[2][2], s[2][3]));
  float d = fmaxf(fmaxf(s[3][0], s[3][1]), fmaxf(s[3][2], s[3][3]));
  return fmaxf(fmaxf(a, b), fmaxf(c, d));
}

// Merged prep: LDS-tiled weight transposes (blocks 0-511), x cvt (512-2559),
// LN1 (2560-3583, 4 rows/block).
__global__ __launch_bounds__(256) void k_prep(
    const float* __restrict__ Wqkv, const float* __restrict__ Wao,
    const float* __restrict__ Wq, const float* __restrict__ Wkv,
    const float* __restrict__ Wo, const float* __restrict__ x,
    const float* __restrict__ qx, const float* __restrict__ ln1g,
    const float* __restrict__ ln1b,
    u16* __restrict__ o_qkv, u16* __restrict__ o_ao, u16* __restrict__ o_q,
    u16* __restrict__ o_kv, u16* __restrict__ o_o, u16* __restrict__ x_bf,
    u16* __restrict__ xn_bf) {
  __shared__ float lds[64][65];
  int bid = blockIdx.x;
  int t = threadIdx.x;
  if (bid < 512) {
    int n_tile = bid >> 3, k_tile = bid & 7;
    int n0 = n_tile * 64, k0 = k_tile * 64;
    const float* in;
    u16* out;
    int N, nbase;
    if (n0 < 1536)      { in = Wqkv; out = o_qkv; N = 1536; nbase = 0; }
    else if (n0 < 2048) { in = Wao;  out = o_ao;  N = 512;  nbase = 1536; }
    else if (n0 < 2560) { in = Wq;   out = o_q;   N = 512;  nbase = 2048; }
    else if (n0 < 3584) { in = Wkv;  out = o_kv;  N = 1024; nbase = 2560; }
    else                { in = Wo;   out = o_o;   N = 512;  nbase = 3584; }
    int nl0 = n0 - nbase;
    int qr = t >> 4, c4 = (t & 15) * 4;
#pragma unroll
    for (int j = 0; j < 4; j++) {
      int kr = qr + j * 16;
      float4 v = *(const float4*)(in + (size_t)(k0 + kr) * N + nl0 + c4);
      lds[kr][c4] = v.x;
      lds[kr][c4 + 1] = v.y;
      lds[kr][c4 + 2] = v.z;
      lds[kr][c4 + 3] = v.w;
    }
    __syncthreads();
#pragma unroll
    for (int j = 0; j < 4; j++) {
      int nr = qr + j * 16;
      u16 o4[4];
#pragma unroll
      for (int i = 0; i < 4; i++) o4[i] = f2bf(lds[c4 + i][nr]);
      *(uint2*)(out + (size_t)(nl0 + nr) * 512 + k0 + c4) = *(uint2*)o4;
    }
  } else if (bid < 2560) {
    size_t i = ((size_t)(bid - 512) * 256 + t) * 8;
    float v[8];
    *(float4*)&v[0] = *(const float4*)(x + i);
    *(float4*)&v[4] = *(const float4*)(x + i + 4);
    u16 o[8];
#pragma unroll
    for (int j = 0; j < 8; j++) o[j] = f2bf(v[j]);
    *(uint4*)(x_bf + i) = *(uint4*)o;
  } else {
    int row = (bid - 2560) * 4 + (t >> 6);
    int lane = t & 63;
    size_t base = (size_t)row * 512 + lane * 8;
    float v[8];
    *(float4*)&v[0] = *(const float4*)(qx + base);
    *(float4*)&v[4] = *(const float4*)(qx + base + 4);
    float s = 0.f, q = 0.f;
#pragma unroll
    for (int j = 0; j < 8; j++) { s += v[j]; q += v[j] * v[j]; }
#pragma unroll
    for (int d = 1; d < 64; d <<= 1) {
      s += __shfl_xor(s, d, 64);
      q += __shfl_xor(q, d, 64);
    }
    float mean = s * (1.f / 512.f);
    float var = q * (1.f / 512.f) - mean * mean;
    float rstd = rsqrtf(var + 1e-5f);
    float gv[8], bv[8];
    *(float4*)&gv[0] = *(const float4*)(ln1g + lane * 8);
    *(float4*)&gv[4] = *(const float4*)(ln1g + lane * 8 + 4);
    *(float4*)&bv[0] = *(const float4*)(ln1b + lane * 8);
    *(float4*)&bv[4] = *(const float4*)(ln1b + lane * 8 + 4);
    u16 ob[8];
#pragma unroll
    for (int j = 0; j < 8; j++)
      ob[j] = f2bf((v[j] - mean) * rstd * gv[j] + bv[j]);
    *(uint4*)(xn_bf + base) = *(uint4*)ob;
  }
}

// LayerNorm over 512 cols (LN2): xin bf16, residual f32; f32 + bf16 outputs.
__global__ __launch_bounds__(64) void k_ln(const u16* __restrict__ xin,
                                           const float* __restrict__ res,
                                           const float* __restrict__ gg,
                                           const float* __restrict__ bb,
                                           float* __restrict__ fout,
                                           u16* __restrict__ bfout) {
  int row = blockIdx.x, t = threadIdx.x;
  size_t base = (size_t)row * 512 + t * 8;
  u16 xv[8];
  *(uint4*)xv = *(const uint4*)(xin + base);
  float v[8];
#pragma unroll
  for (int j = 0; j < 8; j++) v[j] = bf2f(xv[j]);
  {
    float r2[8];
    *(float4*)&r2[0] = *(const float4*)(res + base);
    *(float4*)&r2[4] = *(const float4*)(res + base + 4);
#pragma unroll
    for (int j = 0; j < 8; j++) v[j] += r2[j];
  }
  float s = 0.f, q = 0.f;
#pragma unroll
  for (int j = 0; j < 8; j++) { s += v[j]; q += v[j] * v[j]; }
#pragma unroll
  for (int d = 1; d < 64; d <<= 1) {
    s += __shfl_xor(s, d, 64);
    q += __shfl_xor(q, d, 64);
  }
  float mean = s * (1.f / 512.f);
  float var = q * (1.f / 512.f) - mean * mean;
  float rstd = rsqrtf(var + 1e-5f);
  float gv[8], bv[8];
  *(float4*)&gv[0] = *(const float4*)(gg + t * 8);
  *(float4*)&gv[4] = *(const float4*)(gg + t * 8 + 4);
  *(float4*)&bv[0] = *(const float4*)(bb + t * 8);
  *(float4*)&bv[4] = *(const float4*)(bb + t * 8 + 4);
  float y[8];
  u16 ob[8];
#pragma unroll
  for (int j = 0; j < 8; j++) {
    y[j] = (v[j] - mean) * rstd * gv[j] + bv[j];
    ob[j] = f2bf(y[j]);
  }
  *(float4*)(fout + base) = *(float4*)&y[0];
  *(float4*)(fout + base + 4) = *(float4*)&y[4];
  *(uint4*)(bfout + base) = *(uint4*)ob;
}

// Merged front GEMMs, one launch:
//   blocks 0-511:   kv = x @ Wkv (128x128 tile, KVPACK epilogue -> kpk/vtp)
//   blocks 512-1279: qkv = xn @ Wqkv (64x128 tile)
__global__ __launch_bounds__(256) void k_mm0(
    const u16* __restrict__ xb, const u16* __restrict__ wkv,
    const u16* __restrict__ xn, const u16* __restrict__ wqkv,
    u16* __restrict__ kpk, u16* __restrict__ vtp, u16* __restrict__ qkv) {
  __shared__ u16 As[8192];
  __shared__ u16 Bs[8192];
  const int tid = threadIdx.x;
  const int lane = tid & 63, wid = tid >> 6;
  const int lr = lane & 15, g = lane >> 4;
  const int wr = wid >> 1, wc = wid & 1;
  const int srow = wid * 8 + (lane >> 3);
  const int scol = ((lane & 7) ^ (lane >> 3)) << 3;
  u16* lA = As + wid * 512;
  u16* lB = Bs + wid * 512;
  const size_t rK = (size_t)32 * 512;
  int bid = blockIdx.x;
  if (bid < 512) {
    int bx = bid & 7, by = bid >> 3;
    const int rowBase = by * 128, colBase = bx * 128;
    f32x4 acc[4][4] = {};
    const u16* gA = xb + (size_t)(rowBase + srow) * 512 + scol;
    const u16* gB = wkv + (size_t)(colBase + srow) * 512 + scol;
    for (int k0 = 0; k0 < 512; k0 += 64) {
#pragma unroll
      for (int r = 0; r < 4; r++) async16(lA + r * 2048, gA + r * rK + k0);
#pragma unroll
      for (int r = 0; r < 4; r++) async16(lB + r * 2048, gB + r * rK + k0);
      __syncthreads();
#pragma unroll
      for (int kk = 0; kk < 2; kk++) {
        bf16x8 af[4], bw[4];
#pragma unroll
        for (int fm = 0; fm < 4; fm++) {
          int row = wr * 64 + fm * 16 + lr;
          af[fm] = *(const bf16x8*)((const char*)As + row * 128 +
                                    (((kk * 4 + g) ^ (row & 7)) << 4));
        }
#pragma unroll
        for (int fn = 0; fn < 4; fn++) {
          int row = wc * 64 + fn * 16 + lr;
          bw[fn] = *(const bf16x8*)((const char*)Bs + row * 128 +
                                    (((kk * 4 + g) ^ (row & 7)) << 4));
        }
#pragma unroll
        for (int fm = 0; fm < 4; fm++)
#pragma unroll
          for (int fn = 0; fn < 4; fn++)
            acc[fm][fn] = mfma16(af[fm], bw[fn], acc[fm][fn]);
      }
      __syncthreads();
    }
#pragma unroll
    for (int fm = 0; fm < 4; fm++) {
#pragma unroll
      for (int fn = 0; fn < 4; fn++) {
        int row = rowBase + wr * 64 + fm * 16 + g * 4;
        int col = colBase + wc * 64 + fn * 16 + lr;
        int b = row >> 12, n = row & 4095, kt = n >> 6, key0 = n & 63;
        int h = (col >> 6) & 7, d = col & 63;
        size_t tbase = ((size_t)(((b << 3) + h) << 6) + kt) * 4096;
        if (col < 512) {
          u16* kd = kpk + tbase + (size_t)key0 * 64 + d;
          kd[0] = f2bf(acc[fm][fn][0]);
          kd[64] = f2bf(acc[fm][fn][1]);
          kd[128] = f2bf(acc[fm][fn][2]);
          kd[192] = f2bf(acc[fm][fn][3]);
        } else {
          u16 p4[4] = {f2bf(acc[fm][fn][0]), f2bf(acc[fm][fn][1]),
                       f2bf(acc[fm][fn][2]), f2bf(acc[fm][fn][3])};
          *(uint2*)(vtp + tbase + (size_t)d * 64 + key0) = *(uint2*)p4;
        }
      }
    }
  } else {
    int j = bid - 512;
    int bx = j % 12, by = j / 12;
    const int rowBase = by * 64, colBase = bx * 128;
    f32x4 acc[2][4] = {};
    const u16* gA = xn + (size_t)(rowBase + srow) * 512 + scol;
    const u16* gB = wqkv + (size_t)(colBase + srow) * 512 + scol;
    for (int k0 = 0; k0 < 512; k0 += 64) {
#pragma unroll
      for (int r = 0; r < 2; r++) async16(lA + r * 2048, gA + r * rK + k0);
#pragma unroll
      for (int r = 0; r < 4; r++) async16(lB + r * 2048, gB + r * rK + k0);
      __syncthreads();
#pragma unroll
      for (int kk = 0; kk < 2; kk++) {
        bf16x8 af[2], bw[4];
#pragma unroll
        for (int fm = 0; fm < 2; fm++) {
          int row = wr * 32 + fm * 16 + lr;
          af[fm] = *(const bf16x8*)((const char*)As + row * 128 +
                                    (((kk * 4 + g) ^ (row & 7)) << 4));
        }
#pragma unroll
        for (int fn = 0; fn < 4; fn++) {
          int row = wc * 64 + fn * 16 + lr;
          bw[fn] = *(const bf16x8*)((const char*)Bs + row * 128 +
                                    (((kk * 4 + g) ^ (row & 7)) << 4));
        }
#pragma unroll
        for (int fm = 0; fm < 2; fm++)
#pragma unroll
          for (int fn = 0; fn < 4; fn++)
            acc[fm][fn] = mfma16(af[fm], bw[fn], acc[fm][fn]);
      }
      __syncthreads();
    }
#pragma unroll
    for (int fm = 0; fm < 2; fm++) {
#pragma unroll
      for (int fn = 0; fn < 4; fn++) {
        int row = rowBase + wr * 32 + fm * 16 + g * 4;
        int col = colBase + wc * 64 + fn * 16 + lr;
#pragma unroll
        for (int r = 0; r < 4; r++)
          qkv[(size_t)(row + r) * 1536 + col] = f2bf(acc[fm][fn][r]);
      }
    }
  }
}

// Small GEMM: 64x64 tile, BK=64, 4 waves (2x2, each 32x32).
template <bool BIAS, bool OBF16>
__global__ __launch_bounds__(256) void k_gemm3(const u16* __restrict__ A,
                                               const u16* __restrict__ Bt,
                                               const float* __restrict__ bias,
                                               void* __restrict__ C, int M, int N, int K) {
  __shared__ u16 As[4096];
  __shared__ u16 Bs[4096];
  const int tid = threadIdx.x;
  const int lane = tid & 63, wid = tid >> 6;
  const int lr = lane & 15, g = lane >> 4;
  const int wr = wid >> 1, wc = wid & 1;
  const int rowBase = blockIdx.y * 64, colBase = blockIdx.x * 64;
  f32x4 acc[2][2] = {};
  const int srow = wid * 8 + (lane >> 3);
  const int scol = ((lane & 7) ^ (lane >> 3)) << 3;
  const u16* gA = A + (size_t)(rowBase + srow) * K + scol;
  const u16* gB = Bt + (size_t)(colBase + srow) * K + scol;
  u16* lA = As + wid * 512;
  u16* lB = Bs + wid * 512;
  const size_t rK = (size_t)32 * K;
  for (int k0 = 0; k0 < K; k0 += 64) {
#pragma unroll
    for (int r = 0; r < 2; r++) async16(lA + r * 2048, gA + r * rK + k0);
#pragma unroll
    for (int r = 0; r < 2; r++) async16(lB + r * 2048, gB + r * rK + k0);
    __syncthreads();
#pragma unroll
    for (int kk = 0; kk < 2; kk++) {
      bf16x8 af[2], bw[2];
#pragma unroll
      for (int fm = 0; fm < 2; fm++) {
        int row = wr * 32 + fm * 16 + lr;
        af[fm] = *(const bf16x8*)((const char*)As + row * 128 +
                                  (((kk * 4 + g) ^ (row & 7)) << 4));
      }
#pragma unroll
      for (int fn = 0; fn < 2; fn++) {
        int row = wc * 32 + fn * 16 + lr;
        bw[fn] = *(const bf16x8*)((const char*)Bs + row * 128 +
                                  (((kk * 4 + g) ^ (row & 7)) << 4));
      }
#pragma unroll
      for (int fm = 0; fm < 2; fm++)
#pragma unroll
        for (int fn = 0; fn < 2; fn++)
          acc[fm][fn] = mfma16(af[fm], bw[fn], acc[fm][fn]);
    }
    __syncthreads();
  }
#pragma unroll
  for (int fm = 0; fm < 2; fm++) {
#pragma unroll
    for (int fn = 0; fn < 2; fn++) {
      int row = rowBase + wr * 32 + fm * 16 + g * 4;
      int col = colBase + wc * 32 + fn * 16 + lr;
      float bvv = BIAS ? bias[col] : 0.f;
#pragma unroll
      for (int r = 0; r < 4; r++) {
        float v = acc[fm][fn][r] + bvv;
        if (OBF16)
          ((u16*)C)[(size_t)(row + r) * N + col] = f2bf(v);
        else
          ((float*)C)[(size_t)(row + r) * N + col] = v;
      }
    }
  }
}

// Chunked local attention: one block per (b, h, chunk of 64).
__global__ __launch_bounds__(256) void k_local(const u16* __restrict__ qkv,
                                               u16* __restrict__ oattn) {
  int bid = blockIdx.x;
  int m = bid & 31, h = (bid >> 5) & 7, b = bid >> 8;
  __shared__ u16 Qs[4096], Ks[4096], Vt[4096], Ps[4096];
  int t = threadIdx.x;
  {
    int i = t >> 2, c0 = (t & 3) * 16;
    const u16* base = qkv + (size_t)(b * NQ + m * 64 + i) * 1536 + c0;
    uint4 q0 = *(const uint4*)(base + h * 64);
    uint4 q1 = *(const uint4*)(base + h * 64 + 8);
    uint4 k0 = *(const uint4*)(base + 512 + h * 64);
    uint4 k1 = *(const uint4*)(base + 512 + h * 64 + 8);
    uint4 v0 = *(const uint4*)(base + 1024 + h * 64);
    uint4 v1 = *(const uint4*)(base + 1024 + h * 64 + 8);
    *(uint4*)((char*)Qs + swz(i, c0 * 2)) = q0;
    *(uint4*)((char*)Qs + swz(i, c0 * 2 + 16)) = q1;
    *(uint4*)((char*)Ks + swz(i, c0 * 2)) = k0;
    *(uint4*)((char*)Ks + swz(i, c0 * 2 + 16)) = k1;
    u16 vv[16];
    *(uint4*)&vv[0] = v0;
    *(uint4*)&vv[8] = v1;
#pragma unroll
    for (int j = 0; j < 16; j++) {
      int d = c0 + j;
      *(u16*)((char*)Vt + swz(d, i * 2)) = vv[j];  // Vt[d][key]
    }
  }
  __syncthreads();
  int lane = t & 63, w = t >> 6, lr = lane & 15, g = lane >> 4;
  bf16x8 aq[2];
#pragma unroll
  for (int kk = 0; kk < 2; kk++)
    aq[kk] = *(const bf16x8*)((const char*)Qs + swz(w * 16 + lr, kk * 64 + g * 16));
  f32x4 s[4] = {};
#pragma unroll
  for (int fn = 0; fn < 4; fn++)
#pragma unroll
    for (int kk = 0; kk < 2; kk++) {
      bf16x8 bk = *(const bf16x8*)((const char*)Ks + swz(fn * 16 + lr, kk * 64 + g * 16));
      s[fn] = mfma16(aq[kk], bk, s[fn]);
    }
  float mx[4], sm[4], p[4][4];
#pragma unroll
  for (int r = 0; r < 4; r++)
    mx[r] = fmaxf(fmaxf(s[0][r], s[1][r]), fmaxf(s[2][r], s[3][r]));
#pragma unroll
  for (int d = 1; d < 16; d <<= 1)
#pragma unroll
    for (int r = 0; r < 4; r++) mx[r] = fmaxf(mx[r], __shfl_xor(mx[r], d, 64));
#pragma unroll
  for (int r = 0; r < 4; r++) {
    float a = 0.f;
#pragma unroll
    for (int fn = 0; fn < 4; fn++) {
      p[fn][r] = exp2f((s[fn][r] - mx[r]) * (SCALE * LOG2E));
      a += p[fn][r];
    }
    sm[r] = a;
  }
#pragma unroll
  for (int d = 1; d < 16; d <<= 1)
#pragma unroll
    for (int r = 0; r < 4; r++) sm[r] += __shfl_xor(sm[r], d, 64);
  float rinv[4];
#pragma unroll
  for (int r = 0; r < 4; r++) rinv[r] = 1.f / sm[r];
#pragma unroll
  for (int fn = 0; fn < 4; fn++)
#pragma unroll
    for (int r = 0; r < 4; r++)
      *(u16*)((char*)Ps + swz(w * 16 + g * 4 + r, (fn * 16 + lr) * 2)) =
          f2bf(p[fn][r] * rinv[r]);
  bf16x8 ap[2];
#pragma unroll
  for (int kk = 0; kk < 2; kk++)
    ap[kk] = *(const bf16x8*)((const char*)Ps + swz(w * 16 + lr, kk * 64 + g * 16));
  f32x4 o[4] = {};
#pragma unroll
  for (int fn = 0; fn < 4; fn++)
#pragma unroll
    for (int kk = 0; kk < 2; kk++) {
      bf16x8 bv = *(const bf16x8*)((const char*)Vt + swz(fn * 16 + lr, kk * 64 + g * 16));
      o[fn] = mfma16(ap[kk], bv, o[fn]);
    }
#pragma unroll
  for (int fn = 0; fn < 4; fn++)
#pragma unroll
    for (int r = 0; r < 4; r++)
      oattn[(size_t)(b * NQ + m * 64 + w * 16 + g * 4 + r) * 512 + h * 64 + fn * 16 + lr] =
          f2bf(o[fn][r]);
}

// Flash cross-attention, split-K=4, swapped QK^T, 32 q-rows/wave, MFMA l-sum,
// LDS-staged K/V dbuf, KEY-PERMUTED K staging -> P stays in registers,
// defer-max, setprio, XCD remap. 32KB LDS.
__global__ __launch_bounds__(256, 4) void k_cross(const u16* __restrict__ q,
                                                  const u16* __restrict__ kpk,
                                                  const u16* __restrict__ vtp,
                                                  u16* __restrict__ opart,
                                                  float* __restrict__ ml) {
  int f = blockIdx.x + 16 * blockIdx.y + 256 * blockIdx.z;
  int xcd = f & 7, j = f >> 3;
  int c = xcd + 8 * (j >> 4);
  int qt = j & 15, bh = c & 15, split = c >> 4;
  int b = bh >> 3, h = bh & 7;
  int t = threadIdx.x, lane = t & 63, w = t >> 6, lr = lane & 15, g = lane >> 4;
  __shared__ u16 Ks[2][4096], Vs[2][4096];
  const float cs = SCALE * LOG2E;

  bf16x8 ones;
#pragma unroll
  for (int i = 0; i < 8; i++) ones[i] = (__bf16)1.0f;

  int srow = w * 16 + (lane >> 3);
  int scolb = ((lane & 7) ^ (srow & 7)) << 3;  // u16 units
  int kperm = ((srow >> 5) << 5) + (((srow >> 2) & 3) << 3) +
              (((srow >> 4) & 1) << 2) + (srow & 3);
  int ksoff0 = kperm * 64 + scolb;
  int ksoff1 = ksoff0 + 1024;
  int soff0 = srow * 64 + scolb;
  int soff1 = soff0 + 512;
  const u16* ktiles = kpk + ((size_t)(bh * 64 + split * 16) * 4096);
  const u16* vtiles = vtp + ((size_t)(bh * 64 + split * 16) * 4096);

  const u16* qrowL = q + (size_t)(b * NQ + qt * 128 + w * 32 + lr) * 512 + h * 64;
  const u16* qrowH = qrowL + 16 * 512;
  bf16x8 aqL0 = *(const bf16x8*)(qrowL + g * 8);
  bf16x8 aqL1 = *(const bf16x8*)(qrowL + 32 + g * 8);
  bf16x8 aqH0 = *(const bf16x8*)(qrowH + g * 8);
  bf16x8 aqH1 = *(const bf16x8*)(qrowH + 32 + g * 8);

  f32x4 oL[4] = {}, oH[4] = {};
  f32x4 lsumL = {}, lsumH = {};
  float mL = -1e30f, mH = -1e30f;

  async16(&Ks[0][w * 1024], ktiles + ksoff0);
  async16(&Ks[0][w * 1024 + 512], ktiles + ksoff1);
  async16(&Vs[0][w * 1024], vtiles + soff0);
  async16(&Vs[0][w * 1024 + 512], vtiles + soff1);
  __syncthreads();

  int buf = 0;
  for (int kt = 0; kt < 16; kt++) {
    if (kt < 15) {
      const u16* kn = ktiles + (size_t)(kt + 1) * 4096;
      const u16* vn = vtiles + (size_t)(kt + 1) * 4096;
      async16(&Ks[buf ^ 1][w * 1024], kn + ksoff0);
      async16(&Ks[buf ^ 1][w * 1024 + 512], kn + ksoff1);
      async16(&Vs[buf ^ 1][w * 1024], vn + soff0);
      async16(&Vs[buf ^ 1][w * 1024 + 512], vn + soff1);
    }
    f32x4 stL[4], stH[4];
    __builtin_amdgcn_s_setprio(1);
#pragma unroll
    for (int fm = 0; fm < 4; fm++) {
      bf16x8 bk0 = *(const bf16x8*)((const char*)Ks[buf] + swz(fm * 16 + lr, g * 16));
      bf16x8 bk1 = *(const bf16x8*)((const char*)Ks[buf] + swz(fm * 16 + lr, 64 + g * 16));
      stL[fm] = mfma16(bk0, aqL0, (f32x4){0.f, 0.f, 0.f, 0.f});
      stL[fm] = mfma16(bk1, aqL1, stL[fm]);
      stH[fm] = mfma16(bk0, aqH0, (f32x4){0.f, 0.f, 0.f, 0.f});
      stH[fm] = mfma16(bk1, aqH1, stH[fm]);
    }
    __builtin_amdgcn_s_setprio(0);
    // ---- softmax L (in registers) ----
    float tmL = max16(stL);
    tmL = fmaxf(tmL, __shfl_xor(tmL, 16, 64));
    tmL = fmaxf(tmL, __shfl_xor(tmL, 32, 64));
    if (!__all(tmL <= mL + 22.2f)) {
      float mnew = fmaxf(mL, tmL);
      float corr = exp2f((mL - mnew) * cs);
      mL = mnew;
      float c0 = __shfl(corr, g * 4 + 0, 64);
      float c1 = __shfl(corr, g * 4 + 1, 64);
      float c2 = __shfl(corr, g * 4 + 2, 64);
      float c3 = __shfl(corr, g * 4 + 3, 64);
      lsumL[0] *= c0; lsumL[1] *= c1; lsumL[2] *= c2; lsumL[3] *= c3;
#pragma unroll
      for (int fn = 0; fn < 4; fn++) {
        oL[fn][0] *= c0; oL[fn][1] *= c1; oL[fn][2] *= c2; oL[fn][3] *= c3;
      }
    }
    bf16x8 apL0, apL1;
    {
      float mc = mL * cs;
      union { __bf16 hh[8]; bf16x8 v; } u0, u1;
#pragma unroll
      for (int r = 0; r < 4; r++) {
        u0.hh[r]     = (__bf16)exp2f(stL[0][r] * cs - mc);
        u0.hh[4 + r] = (__bf16)exp2f(stL[1][r] * cs - mc);
        u1.hh[r]     = (__bf16)exp2f(stL[2][r] * cs - mc);
        u1.hh[4 + r] = (__bf16)exp2f(stL[3][r] * cs - mc);
      }
      apL0 = u0.v;
      apL1 = u1.v;
    }
    // ---- softmax H ----
    float tmH = max16(stH);
    tmH = fmaxf(tmH, __shfl_xor(tmH, 16, 64));
    tmH = fmaxf(tmH, __shfl_xor(tmH, 32, 64));
    if (!__all(tmH <= mH + 22.2f)) {
      float mnew = fmaxf(mH, tmH);
      float corr = exp2f((mH - mnew) * cs);
      mH = mnew;
      float c0 = __shfl(corr, g * 4 + 0, 64);
      float c1 = __shfl(corr, g * 4 + 1, 64);
      float c2 = __shfl(corr, g * 4 + 2, 64);
      float c3 = __shfl(corr, g * 4 + 3, 64);
      lsumH[0] *= c0; lsumH[1] *= c1; lsumH[2] *= c2; lsumH[3] *= c3;
#pragma unroll
      for (int fn = 0; fn < 4; fn++) {
        oH[fn][0] *= c0; oH[fn][1] *= c1; oH[fn][2] *= c2; oH[fn][3] *= c3;
      }
    }
    bf16x8 apH0, apH1;
    {
      float mc = mH * cs;
      union { __bf16 hh[8]; bf16x8 v; } u0, u1;
#pragma unroll
      for (int r = 0; r < 4; r++) {
        u0.hh[r]     = (__bf16)exp2f(stH[0][r] * cs - mc);
        u0.hh[4 + r] = (__bf16)exp2f(stH[1][r] * cs - mc);
        u1.hh[r]     = (__bf16)exp2f(stH[2][r] * cs - mc);
        u1.hh[4 + r] = (__bf16)exp2f(stH[3][r] * cs - mc);
      }
      apH0 = u0.v;
      apH1 = u1.v;
    }
    // ---- PV + l-sum via ones-MFMA ----
    __builtin_amdgcn_s_setprio(1);
    lsumL = mfma16(apL0, ones, lsumL);
    lsumL = mfma16(apL1, ones, lsumL);
    lsumH = mfma16(apH0, ones, lsumH);
    lsumH = mfma16(apH1, ones, lsumH);
#pragma unroll
    for (int fn = 0; fn < 4; fn++) {
      bf16x8 bv0 = *(const bf16x8*)((const char*)Vs[buf] + swz(fn * 16 + lr, g * 16));
      bf16x8 bv1 = *(const bf16x8*)((const char*)Vs[buf] + swz(fn * 16 + lr, 64 + g * 16));
      oL[fn] = mfma16(apL0, bv0, oL[fn]);
      oL[fn] = mfma16(apL1, bv1, oL[fn]);
      oH[fn] = mfma16(apH0, bv0, oH[fn]);
      oH[fn] = mfma16(apH1, bv1, oH[fn]);
    }
    __builtin_amdgcn_s_setprio(0);
    __syncthreads();
    buf ^= 1;
  }
  size_t sb = ((size_t)(split * 16 + bh) * NQ) + qt * 128 + w * 32;
  {
    float r0 = 1.f / lsumL[0], r1 = 1.f / lsumL[1];
    float r2 = 1.f / lsumL[2], r3 = 1.f / lsumL[3];
#pragma unroll
    for (int fn = 0; fn < 4; fn++) {
      opart[(sb + g * 4 + 0) * 64 + fn * 16 + lr] = f2bf(oL[fn][0] * r0);
      opart[(sb + g * 4 + 1) * 64 + fn * 16 + lr] = f2bf(oL[fn][1] * r1);
      opart[(sb + g * 4 + 2) * 64 + fn * 16 + lr] = f2bf(oL[fn][2] * r2);
      opart[(sb + g * 4 + 3) * 64 + fn * 16 + lr] = f2bf(oL[fn][3] * r3);
    }
  }
  {
    float r0 = 1.f / lsumH[0], r1 = 1.f / lsumH[1];
    float r2 = 1.f / lsumH[2], r3 = 1.f / lsumH[3];
#pragma unroll
    for (int fn = 0; fn < 4; fn++) {
      opart[(sb + 16 + g * 4 + 0) * 64 + fn * 16 + lr] = f2bf(oH[fn][0] * r0);
      opart[(sb + 16 + g * 4 + 1) * 64 + fn * 16 + lr] = f2bf(oH[fn][1] * r1);
      opart[(sb + 16 + g * 4 + 2) * 64 + fn * 16 + lr] = f2bf(oH[fn][2] * r2);
      opart[(sb + 16 + g * 4 + 3) * 64 + fn * 16 + lr] = f2bf(oH[fn][3] * r3);
    }
  }
  if (g == 0) {
    ml[(sb + lr) * 2] = mL;
    ml[(sb + 16 + lr) * 2] = mH;
  }
  if (lr == 0) {
#pragma unroll
    for (int r = 0; r < 4; r++) {
      ml[(sb + g * 4 + r) * 2 + 1] = lsumL[r];
      ml[(sb + 16 + g * 4 + r) * 2 + 1] = lsumH[r];
    }
  }
}

// Combine 4 split-K partials -> co (bf16, merged-head layout).
__global__ __launch_bounds__(256) void k_comb(const u16* __restrict__ opart,
                                              const float* __restrict__ ml,
                                              u16* __restrict__ co) {
  int idx = blockIdx.x * 256 + threadIdx.x;  // 16*2048*8 = 262144
  int c8 = idx & 7;
  int row = (idx >> 3) & 2047;
  int bh = idx >> 14;
  int b = bh >> 3, h = bh & 7;
  const float cs = SCALE * LOG2E;
  float m[4], l[4];
#pragma unroll
  for (int s = 0; s < 4; s++) {
    size_t rb = ((size_t)(s * 16 + bh) * NQ + row);
    m[s] = ml[rb * 2];
    l[s] = ml[rb * 2 + 1];
  }
  float M = fmaxf(fmaxf(m[0], m[1]), fmaxf(m[2], m[3]));
  float wsum = 0.f, wgt[4];
#pragma unroll
  for (int s = 0; s < 4; s++) {
    wgt[s] = l[s] * exp2f((m[s] - M) * cs);
    wsum += wgt[s];
  }
  float acc[8] = {};
#pragma unroll
  for (int s = 0; s < 4; s++) {
    size_t rb = ((size_t)(s * 16 + bh) * NQ + row);
    uint4 pk = *(const uint4*)(opart + rb * 64 + c8 * 8);
    u16 pe[8];
    *(uint4*)pe = pk;
#pragma unroll
    for (int j = 0; j < 8; j++) acc[j] += wgt[s] * bf2f(pe[j]);
  }
  float rw = 1.f / wsum;
  u16 ob[8];
#pragma unroll
  for (int j = 0; j < 8; j++) ob[j] = f2bf(acc[j] * rw);
  *(uint4*)(co + ((size_t)(b * NQ + row) * 512) + h * 64 + c8 * 8) = *(uint4*)ob;
}

extern "C" void kernel_launch(void* const* d_in, const int* in_sizes, int n_in,
                              void* d_out, int out_size, void* d_ws, size_t ws_size,
                              hipStream_t stream) {
  const float* x    = (const float*)d_in[0];
  const float* qx   = (const float*)d_in[1];
  const float* ln1g = (const float*)d_in[2];
  const float* ln1b = (const float*)d_in[3];
  const float* Wqkv = (const float*)d_in[4];
  const float* Wao  = (const float*)d_in[5];
  const float* bao  = (const float*)d_in[6];
  const float* ln2g = (const float*)d_in[7];
  const float* ln2b = (const float*)d_in[8];
  const float* Wq   = (const float*)d_in[9];
  const float* Wkv  = (const float*)d_in[10];
  const float* Wo   = (const float*)d_in[11];
  const float* bo   = (const float*)d_in[12];
  float* out_p = (float*)d_out;
  float* qin_p = out_p + (size_t)2 * 2048 * 512;

  const size_t MiB = 1048576;
  char* ws = (char*)d_ws;
  u16* w_qkv_t = (u16*)(ws);              // dead after k_mm0
  u16* w_ao_t  = (u16*)(ws + 1572864);    // dead after gemm3-ao
  u16* w_q_t   = (u16*)(ws + 2097152);    // dead after gemm3-q
  u16* w_kv_t  = (u16*)(ws + 2621440);    // dead after k_mm0
  u16* w_o_t   = (u16*)(ws + 3670016);    // alive to end
  float* ml    = (float*)(ws);            // 2 MiB, k_cross -> k_comb
                                          // (overlaps dead w_qkv/w_ao)
  u16* kpk     = (u16*)(ws + 4 * MiB);    // 8 MiB, k_mm0 -> k_cross
  u16* vtp     = (u16*)(ws + 12 * MiB);   // 8 MiB, k_mm0 -> k_cross
  u16* x_bf    = (u16*)(ws + 20 * MiB);   // 8 MiB, k_prep -> k_mm0
  u16* oattn_bf = (u16*)(ws + 20 * MiB);  // 4 MiB, k_local -> gemm-ao (x dead)
  u16* ao_bf   = (u16*)(ws + 24 * MiB);   // 4 MiB, gemm-ao -> ln2
  u16* xn_bf   = (u16*)(ws + 28 * MiB);   // 4 MiB, k_prep -> k_mm0
  u16* qin_bf  = (u16*)(ws + 32 * MiB);   // 4 MiB, ln2 -> gemm-q
  u16* opart   = (u16*)(ws + 20 * MiB);   // 16 MiB, k_cross -> k_comb
  u16* qkv_bf  = (u16*)(ws + 36 * MiB);   // 12 MiB, k_mm0 -> k_local
  u16* q_bf    = (u16*)(ws + 36 * MiB);   // 4 MiB, gemm-q -> k_cross
  u16* co_bf   = (u16*)(ws + 40 * MiB);   // 4 MiB, k_comb -> gemm-out

  // weights transpose (LDS-tiled) + x cvt + LN1, one launch
  k_prep<<<dim3(512 + 2048 + 1024), 256, 0, stream>>>(
      Wqkv, Wao, Wq, Wkv, Wo, x, qx, ln1g, ln1b,
      w_qkv_t, w_ao_t, w_q_t, w_kv_t, w_o_t, x_bf, xn_bf);
  // kv-GEMM (KVPACK) + qkv-GEMM, one launch
  k_mm0<<<dim3(512 + 768), 256, 0, stream>>>(
      x_bf, w_kv_t, xn_bf, w_qkv_t, kpk, vtp, qkv_bf);
  // local chunked attention (x dead -> oattn)
  k_local<<<dim3(512), 256, 0, stream>>>(qkv_bf, oattn_bf);
  // ao = local_out @ Wao + bao (bf16 out)
  k_gemm3<true, true><<<dim3(512 / 64, 4096 / 64), 256, 0, stream>>>(
      oattn_bf, w_ao_t, bao, ao_bf, 4096, 512, 512);
  // q_in = LN2(ao + qx)  (bf16 ao input)
  k_ln<<<dim3(4096), 64, 0, stream>>>(ao_bf, qx, ln2g, ln2b, qin_p, qin_bf);
  // q = q_in @ Wq (qkv dead -> q)
  k_gemm3<false, true><<<dim3(512 / 64, 4096 / 64), 256, 0, stream>>>(
      qin_bf, w_q_t, nullptr, q_bf, 4096, 512, 512);
  // flash cross attention, split-K=4 (register-P)
  k_cross<<<dim3(16, 16, 4), 256, 0, stream>>>(q_bf, kpk, vtp, opart, ml);
  // combine partials (single pass over opart)
  k_comb<<<dim3(262144 / 256), 256, 0, stream>>>(opart, ml, co_bf);
  // out = cross_out @ Wo + bo
  k_gemm3<true, false><<<dim3(512 / 64, 4096 / 64), 256, 0, stream>>>(
      co_bf, w_o_t, bo, out_p, 4096, 512, 512);
}